// Round 6
// baseline (423.984 us; speedup 1.0000x reference)
//
#include <hip/hip_runtime.h>

// MultiHeadAttention: B=2, S=2048, D=1024, H=16, HD=64, scores MULTIPLIED by 64.
// Round 6: convert_W (tiny) -> fused proj (z=3 in one dispatch, x split in staging,
// XOR-swizzled LDS) -> transpose_v -> flash (XCD-aware swizzle, split-K x2,
// XOR-swizzled LDS, register-resident P) -> merge.
// Workspace 73 MiB:
//   0 qh_hi | 8 qh_lo | 16 kh_hi | 24 kh_lo | 32 vhT | 40 vh (dead after transpose)
//   48..60 W halves (4 MiB per z: hi,lo; dead after proj) | Op 40..72 | 72 ml

typedef _Float16 half4 __attribute__((ext_vector_type(4)));
typedef _Float16 half8 __attribute__((ext_vector_type(8)));
typedef float floatx4 __attribute__((ext_vector_type(4)));

#define MFMA_F16(a, b, c) __builtin_amdgcn_mfma_f32_16x16x32_f16((a), (b), (c), 0, 0, 0)

constexpr int SEQ = 2048;
constexpr int DM = 1024;
constexpr int NH = 16;
constexpr int HD = 64;
// 64 * log2(e): fold score scale + base-2 conversion into Q projection
constexpr float QSCALE = 92.33248261689366f;

__device__ inline void split4(const float4 f, half4& h, half4& l) {
  h[0] = (_Float16)f.x; l[0] = (_Float16)(f.x - (float)h[0]);
  h[1] = (_Float16)f.y; l[1] = (_Float16)(f.y - (float)h[1]);
  h[2] = (_Float16)f.z; l[2] = (_Float16)(f.z - (float)h[2]);
  h[3] = (_Float16)f.w; l[3] = (_Float16)(f.w - (float)h[3]);
}

// ---------------- convert weights: fp32 -> fp16 hi (+lo for z<2) ------------
// grid 3072: z = blk>>10. W layout in ws: per z 4 MiB block = [hi 2 MiB][lo 2 MiB]
__global__ __launch_bounds__(256) void convert_w(
    const float* __restrict__ Wq, const float* __restrict__ Wk,
    const float* __restrict__ Wv, _Float16* __restrict__ Wbase)
{
  const int z = blockIdx.x >> 10;
  const int idx = (blockIdx.x & 1023) * 256 + threadIdx.x;   // float4 index
  const float* __restrict__ src = (z == 0) ? Wq : (z == 1) ? Wk : Wv;
  float4 f = ((const float4*)src)[idx];
  half4 h, l; split4(f, h, l);
  _Float16* Wh = Wbase + (size_t)z * 2097152;
  *(half4*)(Wh + (size_t)idx * 4) = h;
  if (z < 2) *(half4*)(Wh + 1048576 + (size_t)idx * 4) = l;
}

// ---------------- fused projection GEMM: y = x @ W^T ----------------
// grid (32, 8, 3); block 256 = 4 waves; 128x128 tile, BK=64, register prefetch.
// x fp32 split to hi/lo in staging; W pre-converted. LDS XOR-swizzled stride 64.
__global__ __launch_bounds__(256, 2) void proj_kernel(
    const float* __restrict__ q, const float* __restrict__ k, const float* __restrict__ v,
    const _Float16* __restrict__ Wbase,
    _Float16* __restrict__ qh_hi, _Float16* __restrict__ qh_lo,
    _Float16* __restrict__ kh_hi, _Float16* __restrict__ kh_lo,
    _Float16* __restrict__ vh)
{
  __shared__ __align__(16) _Float16 Ahs[128][64];
  __shared__ __align__(16) _Float16 Als[128][64];
  __shared__ __align__(16) _Float16 Bhs[128][64];
  __shared__ __align__(16) _Float16 Bls[128][64];

  const int z = blockIdx.z;
  const float* __restrict__ x = (z == 0) ? q : (z == 1) ? k : v;
  const _Float16* __restrict__ Whg = Wbase + (size_t)z * 2097152;
  const _Float16* __restrict__ Wlg = Whg + 1048576;
  const int three = (z != 2);

  const int tid = threadIdx.x;
  const int bm = blockIdx.x;          // 0..31
  const int bn = blockIdx.y;          // 0..7
  const int lane = tid & 63, l15 = lane & 15, quad = lane >> 4;
  const int w = tid >> 6, wm = w >> 1, wn = w & 1;

  // staging geometry: half8-chunk c in [0,1024): row=c>>3, ch=c&7; XOR swizzle
  int rowi[4], chi[4], swc[4];
  #pragma unroll
  for (int i = 0; i < 4; i++) {
    int c = i * 256 + tid;
    rowi[i] = c >> 3; chi[i] = c & 7;
    swc[i] = (chi[i] ^ (rowi[i] & 7)) * 8;
  }

  // prefetch registers
  float4 pa[4][2];     // A: two float4 per half8-chunk
  half8 pbh[4], pbl[4];
  #pragma unroll
  for (int i = 0; i < 4; i++) {
    const float* ar = x + (size_t)(bm * 128 + rowi[i]) * DM + chi[i] * 8;
    pa[i][0] = *(const float4*)ar;
    pa[i][1] = *(const float4*)(ar + 4);
    pbh[i] = *(const half8*)(Whg + (size_t)(bn * 128 + rowi[i]) * DM + chi[i] * 8);
    if (three)
      pbl[i] = *(const half8*)(Wlg + (size_t)(bn * 128 + rowi[i]) * DM + chi[i] * 8);
  }

  floatx4 acc[4][4];
  #pragma unroll
  for (int mt = 0; mt < 4; mt++)
    #pragma unroll
    for (int nt = 0; nt < 4; nt++)
      acc[mt][nt] = (floatx4){0.f, 0.f, 0.f, 0.f};

  for (int kk = 0; kk < DM; kk += 64) {
    __syncthreads();
    #pragma unroll
    for (int i = 0; i < 4; i++) {
      half4 h0, l0, h1, l1;
      split4(pa[i][0], h0, l0);
      split4(pa[i][1], h1, l1);
      half8 hh, ll;
      #pragma unroll
      for (int j = 0; j < 4; j++) { hh[j] = h0[j]; hh[j + 4] = h1[j]; ll[j] = l0[j]; ll[j + 4] = l1[j]; }
      *(half8*)&Ahs[rowi[i]][swc[i]] = hh;
      *(half8*)&Als[rowi[i]][swc[i]] = ll;
      *(half8*)&Bhs[rowi[i]][swc[i]] = pbh[i];
      if (three) *(half8*)&Bls[rowi[i]][swc[i]] = pbl[i];
    }
    if (kk + 64 < DM) {
      #pragma unroll
      for (int i = 0; i < 4; i++) {
        const float* ar = x + (size_t)(bm * 128 + rowi[i]) * DM + kk + 64 + chi[i] * 8;
        pa[i][0] = *(const float4*)ar;
        pa[i][1] = *(const float4*)(ar + 4);
        pbh[i] = *(const half8*)(Whg + (size_t)(bn * 128 + rowi[i]) * DM + kk + 64 + chi[i] * 8);
        if (three)
          pbl[i] = *(const half8*)(Wlg + (size_t)(bn * 128 + rowi[i]) * DM + kk + 64 + chi[i] * 8);
      }
    }
    __syncthreads();

    #pragma unroll
    for (int kc = 0; kc < 2; kc++) {
      const int swz = ((kc * 4 + quad) ^ (l15 & 7)) * 8;   // row&7 == l15&7
      half8 ah[4], bh_[4], al[4], bl[4];
      #pragma unroll
      for (int t = 0; t < 4; t++) {
        ah[t]  = *(const half8*)&Ahs[wm * 64 + t * 16 + l15][swz];
        bh_[t] = *(const half8*)&Bhs[wn * 64 + t * 16 + l15][swz];
        if (three) {
          al[t] = *(const half8*)&Als[wm * 64 + t * 16 + l15][swz];
          bl[t] = *(const half8*)&Bls[wn * 64 + t * 16 + l15][swz];
        }
      }
      if (three) {
        #pragma unroll
        for (int mt = 0; mt < 4; mt++)
          #pragma unroll
          for (int nt = 0; nt < 4; nt++) {
            floatx4 t0 = MFMA_F16(ah[mt], bh_[nt], acc[mt][nt]);
            t0 = MFMA_F16(ah[mt], bl[nt], t0);
            acc[mt][nt] = MFMA_F16(al[mt], bh_[nt], t0);
          }
      } else {
        #pragma unroll
        for (int mt = 0; mt < 4; mt++)
          #pragma unroll
          for (int nt = 0; nt < 4; nt++)
            acc[mt][nt] = MFMA_F16(ah[mt], bh_[nt], acc[mt][nt]);
      }
    }
  }

  const float scale = (z == 0) ? QSCALE : 1.0f;
  _Float16* yh = (z == 0) ? qh_hi : (z == 1) ? kh_hi : vh;
  _Float16* yl = (z == 0) ? qh_lo : kh_lo;
  #pragma unroll
  for (int mt = 0; mt < 4; mt++)
    #pragma unroll
    for (int nt = 0; nt < 4; nt++)
      #pragma unroll
      for (int r = 0; r < 4; r++) {
        int gm = bm * 128 + wm * 64 + mt * 16 + quad * 4 + r;   // (b,s)
        int gn = bn * 128 + wn * 64 + nt * 16 + l15;            // h*64+d
        int b = gm >> 11, s = gm & 2047;
        int h = gn >> 6, d = gn & 63;
        size_t idx = ((size_t)(b * NH + h) * SEQ + s) * HD + d;
        float val = acc[mt][nt][r] * scale;
        _Float16 hi = (_Float16)val;
        yh[idx] = hi;
        if (three) yl[idx] = (_Float16)(val - (float)hi);
      }
}

// ---------------- vh [b,h,s,64] -> vhT [b,h,64,perm(s)] ----------------
// perm within 32-group: s = 32c+16a+4q+b -> pos = 32c+8q+4a+b, so flash PV
// A-fragments (key order 32kc+16(j>>2)+4quad+(j&3)) are contiguous b128 reads.
__global__ __launch_bounds__(256) void transpose_v(const _Float16* __restrict__ vh,
                                                   _Float16* __restrict__ vhT)
{
  __shared__ __align__(16) _Float16 T[128][72];
  const int bh = blockIdx.x, sc = blockIdx.y, tid = threadIdx.x;
  const _Float16* src = vh + ((size_t)bh * SEQ + sc * 128) * HD;
  #pragma unroll
  for (int i = 0; i < 4; i++) {
    int c = i * 256 + tid, row = c >> 3, off = (c & 7) * 8;
    *(half8*)&T[row][off] = *(const half8*)(src + (size_t)row * HD + off);
  }
  __syncthreads();
  _Float16* dst = vhT + (size_t)bh * HD * SEQ + sc * 128;
  #pragma unroll
  for (int i = 0; i < 4; i++) {
    int c = i * 256 + tid, hd = c >> 4, off = (c & 15) * 8;
    int base32 = off & ~31, qsel = (off >> 3) & 3;
    half8 vv;
    #pragma unroll
    for (int j = 0; j < 8; j++) {
      int s_local = base32 + 16 * (j >> 2) + 4 * qsel + (j & 3);
      vv[j] = T[s_local][hd];
    }
    *(half8*)(dst + (size_t)hd * SEQ + off) = vv;
  }
}

// ---------------- flash attention v6: XCD swizzle + split-K x2 --------------
// 1-D grid 1024; bh = (id&7) + 8*((id>>3)&3) pins each bh's K/V to one XCD L2.
// 4 waves, 32 q/wave; LDS XOR-swizzled; P register-resident via key perm.
__global__ __launch_bounds__(256, 4) void flash_kernel(
    const _Float16* __restrict__ qh_hi, const _Float16* __restrict__ qh_lo,
    const _Float16* __restrict__ kh_hi, const _Float16* __restrict__ kh_lo,
    const _Float16* __restrict__ vhT, float* __restrict__ Op, float2* __restrict__ ml)
{
  __shared__ __align__(16) _Float16 Kh[64][64];
  __shared__ __align__(16) _Float16 Kl[64][64];
  __shared__ __align__(16) _Float16 Vt[64][64];   // [d][permuted key]

  const int id = blockIdx.x;
  const int seq_ = id >> 3;
  const int bh = (id & 7) + 8 * (seq_ & 3);       // 0..31, pinned to XCD id&7
  const int rem = seq_ >> 2;
  const int qb = rem & 15;                        // 0..15
  const int kh = rem >> 4;                        // 0..1
  const int tid = threadIdx.x;
  const int wq = tid >> 6;
  const int lane = tid & 63, l15 = lane & 15, quad = lane >> 4;

  const size_t bh_off = (size_t)bh * SEQ * HD;
  const _Float16* __restrict__ kh_p = kh_hi + bh_off;
  const _Float16* __restrict__ kl_p = kh_lo + bh_off;
  const _Float16* __restrict__ vt_p = vhT + (size_t)bh * HD * SEQ;
  const int qrow0 = qb * 128 + wq * 32;

  // Q as B-operand fragments: lane holds n=q=l15, k=d=kc*32+quad*8+j
  half8 bqh[2][2], bql[2][2];         // [g][kc]
  #pragma unroll
  for (int g = 0; g < 2; g++) {
    const _Float16* qp_h = qh_hi + bh_off + (size_t)(qrow0 + g * 16 + l15) * HD;
    const _Float16* qp_l = qh_lo + bh_off + (size_t)(qrow0 + g * 16 + l15) * HD;
    #pragma unroll
    for (int kc = 0; kc < 2; kc++) {
      bqh[g][kc] = *(const half8*)(qp_h + kc * 32 + quad * 8);
      bql[g][kc] = *(const half8*)(qp_l + kc * 32 + quad * 8);
    }
  }

  // staging geometry (512 chunks per array): c0=tid, c1=tid+256
  const int row0 = tid >> 3, ch0 = tid & 7, sw0 = (ch0 ^ (row0 & 7)) * 8;
  const int row1 = row0 + 32, sw1 = sw0;          // row1&7 == row0&7

  float m_[2] = {-3.0e38f, -3.0e38f};
  float l_[2] = {0.f, 0.f};
  floatx4 Oacc[2][4];
  #pragma unroll
  for (int g = 0; g < 2; g++)
    #pragma unroll
    for (int nd = 0; nd < 4; nd++) Oacc[g][nd] = (floatx4){0.f, 0.f, 0.f, 0.f};

  const int kt0 = kh * 16;
  for (int kt = kt0; kt < kt0 + 16; kt++) {
    const int kbase = kt * 64;
    __syncthreads();
    {
      half8 t0 = *(const half8*)(kh_p + (size_t)(kbase + row0) * HD + ch0 * 8);
      half8 t1 = *(const half8*)(kh_p + (size_t)(kbase + row1) * HD + ch0 * 8);
      half8 t2 = *(const half8*)(kl_p + (size_t)(kbase + row0) * HD + ch0 * 8);
      half8 t3 = *(const half8*)(kl_p + (size_t)(kbase + row1) * HD + ch0 * 8);
      half8 t4 = *(const half8*)(vt_p + (size_t)row0 * SEQ + kbase + ch0 * 8);
      half8 t5 = *(const half8*)(vt_p + (size_t)row1 * SEQ + kbase + ch0 * 8);
      *(half8*)&Kh[row0][sw0] = t0;
      *(half8*)&Kh[row1][sw1] = t1;
      *(half8*)&Kl[row0][sw0] = t2;
      *(half8*)&Kl[row1][sw1] = t3;
      *(half8*)&Vt[row0][sw0] = t4;
      *(half8*)&Vt[row1][sw1] = t5;
    }
    __syncthreads();

    // S^T = K·Q^T (3-term split fp16), both q-groups share K fragments
    floatx4 sacc[2][4];
    #pragma unroll
    for (int nt = 0; nt < 4; nt++) {
      const int r7 = l15 & 7;
      half8 akh0 = *(const half8*)&Kh[nt * 16 + l15][((0 * 4 + quad) ^ r7) * 8];
      half8 akh1 = *(const half8*)&Kh[nt * 16 + l15][((1 * 4 + quad) ^ r7) * 8];
      half8 akl0 = *(const half8*)&Kl[nt * 16 + l15][((0 * 4 + quad) ^ r7) * 8];
      half8 akl1 = *(const half8*)&Kl[nt * 16 + l15][((1 * 4 + quad) ^ r7) * 8];
      #pragma unroll
      for (int g = 0; g < 2; g++) {
        floatx4 s4 = (floatx4){0.f, 0.f, 0.f, 0.f};
        s4 = MFMA_F16(akh0, bqh[g][0], s4);
        s4 = MFMA_F16(akh1, bqh[g][1], s4);
        s4 = MFMA_F16(akh0, bql[g][0], s4);
        s4 = MFMA_F16(akh1, bql[g][1], s4);
        s4 = MFMA_F16(akl0, bqh[g][0], s4);
        s4 = MFMA_F16(akl1, bqh[g][1], s4);
        sacc[g][nt] = s4;
      }
    }

    #pragma unroll
    for (int g = 0; g < 2; g++) {
      // online softmax over 64 keys: in-lane + 2 cross-quad shuffles
      float rmax = sacc[g][0][0];
      #pragma unroll
      for (int nt = 0; nt < 4; nt++)
        #pragma unroll
        for (int r = 0; r < 4; r++) rmax = fmaxf(rmax, sacc[g][nt][r]);
      rmax = fmaxf(rmax, __shfl_xor(rmax, 16, 64));
      rmax = fmaxf(rmax, __shfl_xor(rmax, 32, 64));
      const float mnew = fmaxf(m_[g], rmax);
      const float alpha = exp2f(m_[g] - mnew);
      m_[g] = mnew;

      float rsum = 0.f;
      #pragma unroll
      for (int nt = 0; nt < 4; nt++)
        #pragma unroll
        for (int r = 0; r < 4; r++) {
          float p = exp2f(sacc[g][nt][r] - mnew);
          sacc[g][nt][r] = p;
          rsum += p;
        }
      rsum += __shfl_xor(rsum, 16, 64);
      rsum += __shfl_xor(rsum, 32, 64);
      l_[g] = l_[g] * alpha + rsum;

      // P pack for PV B-operand: bp8[kc][j] = p[2kc + (j>>2)][j&3] (in-lane)
      half8 bp8[2];
      #pragma unroll
      for (int kc = 0; kc < 2; kc++)
        #pragma unroll
        for (int j = 0; j < 8; j++)
          bp8[kc][j] = (_Float16)sacc[g][2 * kc + (j >> 2)][j & 3];

      const int r7 = l15 & 7;
      #pragma unroll
      for (int nd = 0; nd < 4; nd++) {
        half8 av0 = *(const half8*)&Vt[nd * 16 + l15][((0 * 4 + quad) ^ r7) * 8];
        half8 av1 = *(const half8*)&Vt[nd * 16 + l15][((1 * 4 + quad) ^ r7) * 8];
        Oacc[g][nd][0] *= alpha; Oacc[g][nd][1] *= alpha;
        Oacc[g][nd][2] *= alpha; Oacc[g][nd][3] *= alpha;
        Oacc[g][nd] = MFMA_F16(av0, bp8[0], Oacc[g][nd]);
        Oacc[g][nd] = MFMA_F16(av1, bp8[1], Oacc[g][nd]);
      }
    }
  }

  // epilogue: unnormalized O^T partial + (m,l)
  const size_t fqbase = (size_t)bh * SEQ + qrow0;
  #pragma unroll
  for (int g = 0; g < 2; g++) {
    const size_t fq = fqbase + g * 16 + l15;
    float* ob = Op + ((size_t)kh * 65536 + fq) * HD;
    #pragma unroll
    for (int nd = 0; nd < 4; nd++) {
      float4 vv;
      vv.x = Oacc[g][nd][0]; vv.y = Oacc[g][nd][1];
      vv.z = Oacc[g][nd][2]; vv.w = Oacc[g][nd][3];
      *(float4*)(ob + nd * 16 + quad * 4) = vv;
    }
    if (quad == 0) ml[kh * 65536 + fq] = make_float2(m_[g], l_[g]);
  }
}

// ---------------- merge the two split-K partials ----------------
__global__ __launch_bounds__(256) void merge_kernel(const float* __restrict__ Op,
                                                    const float2* __restrict__ ml,
                                                    float* __restrict__ out)
{
  const int tid = threadIdx.x;
  const int fq = blockIdx.x * 64 + (tid >> 2);
  const int dp = (tid & 3) * 16;
  float2 m0 = ml[fq], m1 = ml[65536 + fq];
  float M = fmaxf(m0.x, m1.x);
  float w0 = exp2f(m0.x - M), w1 = exp2f(m1.x - M);
  float rinv = 1.0f / (m0.y * w0 + m1.y * w1);
  int bh = fq >> 11, s = fq & 2047, b = bh >> 4, h = bh & 15;
  float* ob = out + ((size_t)(b * SEQ + s)) * DM + h * HD + dp;
  const float* p0 = Op + (size_t)fq * HD + dp;
  const float* p1 = p0 + (size_t)65536 * HD;
  #pragma unroll
  for (int j = 0; j < 4; j++) {
    float4 a = *(const float4*)(p0 + 4 * j);
    float4 c = *(const float4*)(p1 + 4 * j);
    float4 r;
    r.x = (a.x * w0 + c.x * w1) * rinv;
    r.y = (a.y * w0 + c.y * w1) * rinv;
    r.z = (a.z * w0 + c.z * w1) * rinv;
    r.w = (a.w * w0 + c.w * w1) * rinv;
    *(float4*)(ob + 4 * j) = r;
  }
}

extern "C" void kernel_launch(void* const* d_in, const int* in_sizes, int n_in,
                              void* d_out, int out_size, void* d_ws, size_t ws_size,
                              hipStream_t stream) {
  const float* q  = (const float*)d_in[0];
  const float* k  = (const float*)d_in[1];
  const float* v  = (const float*)d_in[2];
  const float* Wq = (const float*)d_in[3];
  const float* Wk = (const float*)d_in[4];
  const float* Wv = (const float*)d_in[5];
  float* out = (float*)d_out;

  char* W = (char*)d_ws;
  const size_t MiB = 1ull << 20;
  _Float16* qh_hi = (_Float16*)(W + 0 * MiB);
  _Float16* qh_lo = (_Float16*)(W + 8 * MiB);
  _Float16* kh_hi = (_Float16*)(W + 16 * MiB);
  _Float16* kh_lo = (_Float16*)(W + 24 * MiB);
  _Float16* vhT   = (_Float16*)(W + 32 * MiB);
  _Float16* vh    = (_Float16*)(W + 40 * MiB);  // dead after transpose_v
  _Float16* Wbase = (_Float16*)(W + 48 * MiB);  // 12 MiB; dead after proj
  float*    Op    = (float*)  (W + 40 * MiB);   // 2 x 16 MiB, aliases vh/Wbase
  float2*   mlp   = (float2*) (W + 72 * MiB);   // 1 MiB; total 73 MiB

  convert_w<<<3072, 256, 0, stream>>>(Wq, Wk, Wv, Wbase);
  proj_kernel<<<dim3(32, 8, 3), 256, 0, stream>>>(q, k, v, Wbase,
                                                  qh_hi, qh_lo, kh_hi, kh_lo, vh);
  transpose_v<<<dim3(32, 16), 256, 0, stream>>>(vh, vhT);
  flash_kernel<<<1024, 256, 0, stream>>>(qh_hi, qh_lo, kh_hi, kh_lo, vhT, Op, mlp);
  merge_kernel<<<1024, 256, 0, stream>>>(Op, mlp, out);
}

// Round 7
// 321.836 us; speedup vs baseline: 1.3174x; 1.3174x over previous
//
#include <hip/hip_runtime.h>

// MultiHeadAttention: B=2, S=2048, D=1024, H=16, HD=64, scores MULTIPLIED by 64.
// Round 7: converts (pre-split fp32->fp16 hi/lo) -> 3x proj (BK=64,
// global_load_lds width-16 staging with XOR image via lane->global chunk perm)
// -> transpose_v -> flash (XCD-pinned, split-K x2, global_load_lds staging,
// register-resident P) -> merge.
// LDS image: row r, logical chunk c stored at col (c ^ (r&7)) -- 2-way banks (free).
// Workspace 73 MiB: 0 qh_hi | 8 qh_lo | 16 kh_hi | 24 kh_lo | 32 vhT | 40 vh
//   | 48 xh | 56 xl | 64 Wh | 66 Wl ; Op aliases 40..72 ; 72 ml.

typedef _Float16 half4 __attribute__((ext_vector_type(4)));
typedef _Float16 half8 __attribute__((ext_vector_type(8)));
typedef float floatx4 __attribute__((ext_vector_type(4)));

#define MFMA_F16(a, b, c) __builtin_amdgcn_mfma_f32_16x16x32_f16((a), (b), (c), 0, 0, 0)

constexpr int SEQ = 2048;
constexpr int DM = 1024;
constexpr int NH = 16;
constexpr int HD = 64;
// 64 * log2(e): fold score scale + base-2 conversion into Q projection
constexpr float QSCALE = 92.33248261689366f;

// async 16B/lane global->LDS copy; LDS dest = wave-uniform base + lane*16
__device__ __forceinline__ void gl2lds16(const _Float16* g, _Float16* l) {
  __builtin_amdgcn_global_load_lds(
      (const __attribute__((address_space(1))) void*)g,
      (__attribute__((address_space(3))) void*)l, 16, 0, 0);
}

__device__ inline void split4(const float4 f, half4& h, half4& l) {
  h[0] = (_Float16)f.x; l[0] = (_Float16)(f.x - (float)h[0]);
  h[1] = (_Float16)f.y; l[1] = (_Float16)(f.y - (float)h[1]);
  h[2] = (_Float16)f.z; l[2] = (_Float16)(f.z - (float)h[2]);
  h[3] = (_Float16)f.w; l[3] = (_Float16)(f.w - (float)h[3]);
}

// ---------------- convert: fp32 -> fp16 hi (+lo) ----------------
// blocks 0..4095: x (4M floats); blocks 4096..5119: W (1M floats)
__global__ __launch_bounds__(256) void convert_kernel(
    const float* __restrict__ x, const float* __restrict__ W,
    _Float16* __restrict__ xh, _Float16* __restrict__ xl,
    _Float16* __restrict__ Wh, _Float16* __restrict__ Wl, int do_lo)
{
  if (blockIdx.x < 4096) {
    int idx = blockIdx.x * 256 + threadIdx.x;
    float4 f = ((const float4*)x)[idx];
    half4 h, l; split4(f, h, l);
    *(half4*)(xh + (size_t)idx * 4) = h;
    if (do_lo) *(half4*)(xl + (size_t)idx * 4) = l;
  } else {
    int idx = (blockIdx.x - 4096) * 256 + threadIdx.x;
    float4 f = ((const float4*)W)[idx];
    half4 h, l; split4(f, h, l);
    *(half4*)(Wh + (size_t)idx * 4) = h;
    if (do_lo) *(half4*)(Wl + (size_t)idx * 4) = l;
  }
}

// ---------------- projection GEMM: y = A @ B^T (pre-converted fp16) ---------
// 128x128 tile, BK=64, global_load_lds staging (m97-style 2-barrier loop).
// three=1: 3-term split-fp16, writes yh+yl; three=0: single-term, yh only.
__global__ __launch_bounds__(256, 1) void proj_kernel(
    const _Float16* __restrict__ Ahg, const _Float16* __restrict__ Alg,
    const _Float16* __restrict__ Bhg, const _Float16* __restrict__ Blg,
    _Float16* __restrict__ yh, _Float16* __restrict__ yl,
    float scale, int three)
{
  __shared__ __align__(16) _Float16 Ahs[128][64];
  __shared__ __align__(16) _Float16 Als[128][64];
  __shared__ __align__(16) _Float16 Bhs[128][64];
  __shared__ __align__(16) _Float16 Bls[128][64];

  const int tid = threadIdx.x;
  const int bm = blockIdx.x;          // 0..31
  const int bn = blockIdx.y;          // 0..7
  const int lane = tid & 63, l15 = lane & 15, quad = lane >> 4;
  const int w = tid >> 6, wm = w >> 1, wn = w & 1;

  // staging: wave w stages groups g = 4w+i (8 rows x 1 KiB each) of each array.
  // lane L: row-in-group = L>>3, fetches logical chunk (L&7)^(L>>3) -> XOR image.
  const int r8 = lane >> 3;
  const int cp8 = (((lane & 7) ^ r8)) * 8;    // half offset within row
  int grow[4]; _Float16* la[4]; _Float16* lal[4]; _Float16* lb[4]; _Float16* lbl[4];
  #pragma unroll
  for (int i = 0; i < 4; i++) {
    const int g = w * 4 + i;
    grow[i] = g * 8 + r8;                     // row 0..127 (per-lane)
    la[i]  = &Ahs[0][0] + g * 512;            // wave-uniform LDS bases
    lal[i] = &Als[0][0] + g * 512;
    lb[i]  = &Bhs[0][0] + g * 512;
    lbl[i] = &Bls[0][0] + g * 512;
  }

  floatx4 acc[4][4];
  #pragma unroll
  for (int mt = 0; mt < 4; mt++)
    #pragma unroll
    for (int nt = 0; nt < 4; nt++)
      acc[mt][nt] = (floatx4){0.f, 0.f, 0.f, 0.f};

  for (int kk = 0; kk < DM; kk += 64) {
    __syncthreads();                          // prior tile's reads complete
    #pragma unroll
    for (int i = 0; i < 4; i++) {
      const size_t ga = (size_t)(bm * 128 + grow[i]) * DM + kk + cp8;
      const size_t gb = (size_t)(bn * 128 + grow[i]) * DM + kk + cp8;
      gl2lds16(Ahg + ga, la[i]);
      gl2lds16(Bhg + gb, lb[i]);
      if (three) {
        gl2lds16(Alg + ga, lal[i]);
        gl2lds16(Blg + gb, lbl[i]);
      }
    }
    __syncthreads();                          // vmcnt(0) drain: tile visible

    #pragma unroll
    for (int kc = 0; kc < 2; kc++) {
      const int swz = ((kc * 4 + quad) ^ (l15 & 7)) * 8;
      half8 ah[4], bh_[4], al[4], bl[4];
      #pragma unroll
      for (int t = 0; t < 4; t++) {
        ah[t]  = *(const half8*)&Ahs[wm * 64 + t * 16 + l15][swz];
        bh_[t] = *(const half8*)&Bhs[wn * 64 + t * 16 + l15][swz];
        if (three) {
          al[t] = *(const half8*)&Als[wm * 64 + t * 16 + l15][swz];
          bl[t] = *(const half8*)&Bls[wn * 64 + t * 16 + l15][swz];
        }
      }
      if (three) {
        #pragma unroll
        for (int mt = 0; mt < 4; mt++)
          #pragma unroll
          for (int nt = 0; nt < 4; nt++) {
            floatx4 t0 = MFMA_F16(ah[mt], bh_[nt], acc[mt][nt]);
            t0 = MFMA_F16(ah[mt], bl[nt], t0);
            acc[mt][nt] = MFMA_F16(al[mt], bh_[nt], t0);
          }
      } else {
        #pragma unroll
        for (int mt = 0; mt < 4; mt++)
          #pragma unroll
          for (int nt = 0; nt < 4; nt++)
            acc[mt][nt] = MFMA_F16(ah[mt], bh_[nt], acc[mt][nt]);
      }
    }
  }

  #pragma unroll
  for (int mt = 0; mt < 4; mt++)
    #pragma unroll
    for (int nt = 0; nt < 4; nt++)
      #pragma unroll
      for (int r = 0; r < 4; r++) {
        int gm = bm * 128 + wm * 64 + mt * 16 + quad * 4 + r;   // (b,s)
        int gn = bn * 128 + wn * 64 + nt * 16 + l15;            // h*64+d
        int b = gm >> 11, s = gm & 2047;
        int h = gn >> 6, d = gn & 63;
        size_t idx = ((size_t)(b * NH + h) * SEQ + s) * HD + d;
        float val = acc[mt][nt][r] * scale;
        _Float16 hi = (_Float16)val;
        yh[idx] = hi;
        if (three) yl[idx] = (_Float16)(val - (float)hi);
      }
}

// ---------------- vh [b,h,s,64] -> vhT [b,h,64,perm(s)] ----------------
// perm within 32-group: s = 32c+16a+4q+b -> pos = 32c+8q+4a+b, so flash PV
// A-fragments (key order 32kc+16(j>>2)+4quad+(j&3)) are contiguous b128 reads.
__global__ __launch_bounds__(256) void transpose_v(const _Float16* __restrict__ vh,
                                                   _Float16* __restrict__ vhT)
{
  __shared__ __align__(16) _Float16 T[128][72];
  const int bh = blockIdx.x, sc = blockIdx.y, tid = threadIdx.x;
  const _Float16* src = vh + ((size_t)bh * SEQ + sc * 128) * HD;
  #pragma unroll
  for (int i = 0; i < 4; i++) {
    int c = i * 256 + tid, row = c >> 3, off = (c & 7) * 8;
    *(half8*)&T[row][off] = *(const half8*)(src + (size_t)row * HD + off);
  }
  __syncthreads();
  _Float16* dst = vhT + (size_t)bh * HD * SEQ + sc * 128;
  #pragma unroll
  for (int i = 0; i < 4; i++) {
    int c = i * 256 + tid, hd = c >> 4, off = (c & 15) * 8;
    int base32 = off & ~31, qsel = (off >> 3) & 3;
    half8 vv;
    #pragma unroll
    for (int j = 0; j < 8; j++) {
      int s_local = base32 + 16 * (j >> 2) + 4 * qsel + (j & 3);
      vv[j] = T[s_local][hd];
    }
    *(half8*)(dst + (size_t)hd * SEQ + off) = vv;
  }
}

// ---------------- flash attention v7: XCD pin + split-K x2 + async staging --
// 1-D grid 1024; bh = (id&7) + 8*((id>>3)&3) pins each bh's K/V to one XCD L2.
// 4 waves, 32 q/wave; LDS XOR image via global_load_lds; P register-resident.
__global__ __launch_bounds__(256, 4) void flash_kernel(
    const _Float16* __restrict__ qh_hi, const _Float16* __restrict__ qh_lo,
    const _Float16* __restrict__ kh_hi, const _Float16* __restrict__ kh_lo,
    const _Float16* __restrict__ vhT, float* __restrict__ Op, float2* __restrict__ ml)
{
  __shared__ __align__(16) _Float16 Kh[64][64];
  __shared__ __align__(16) _Float16 Kl[64][64];
  __shared__ __align__(16) _Float16 Vt[64][64];   // [d][permuted key]

  const int id = blockIdx.x;
  const int seq_ = id >> 3;
  const int bh = (id & 7) + 8 * (seq_ & 3);       // 0..31, pinned to XCD id&7
  const int rem = seq_ >> 2;
  const int qb = rem & 15;                        // 0..15
  const int kh = rem >> 4;                        // 0..1
  const int tid = threadIdx.x;
  const int wq = tid >> 6;
  const int lane = tid & 63, l15 = lane & 15, quad = lane >> 4;

  const size_t bh_off = (size_t)bh * SEQ * HD;
  const _Float16* __restrict__ kh_p = kh_hi + bh_off;
  const _Float16* __restrict__ kl_p = kh_lo + bh_off;
  const _Float16* __restrict__ vt_p = vhT + (size_t)bh * HD * SEQ;
  const int qrow0 = qb * 128 + wq * 32;

  // Q as B-operand fragments: lane holds n=q=l15, k=d=kc*32+quad*8+j
  half8 bqh[2][2], bql[2][2];         // [g][kc]
  #pragma unroll
  for (int g = 0; g < 2; g++) {
    const _Float16* qp_h = qh_hi + bh_off + (size_t)(qrow0 + g * 16 + l15) * HD;
    const _Float16* qp_l = qh_lo + bh_off + (size_t)(qrow0 + g * 16 + l15) * HD;
    #pragma unroll
    for (int kc = 0; kc < 2; kc++) {
      bqh[g][kc] = *(const half8*)(qp_h + kc * 32 + quad * 8);
      bql[g][kc] = *(const half8*)(qp_l + kc * 32 + quad * 8);
    }
  }

  // staging: wave wq covers groups 2wq, 2wq+1 per array (8 rows x 1 KiB each)
  const int r8 = lane >> 3;
  const int cp8 = ((lane & 7) ^ r8) * 8;

  float m_[2] = {-3.0e38f, -3.0e38f};
  float l_[2] = {0.f, 0.f};
  floatx4 Oacc[2][4];
  #pragma unroll
  for (int g = 0; g < 2; g++)
    #pragma unroll
    for (int nd = 0; nd < 4; nd++) Oacc[g][nd] = (floatx4){0.f, 0.f, 0.f, 0.f};

  const int kt0 = kh * 16;
  for (int kt = kt0; kt < kt0 + 16; kt++) {
    const int kbase = kt * 64;
    __syncthreads();
    #pragma unroll
    for (int i = 0; i < 2; i++) {
      const int g = wq * 2 + i;
      const int r = g * 8 + r8;
      gl2lds16(kh_p + (size_t)(kbase + r) * HD + cp8, &Kh[0][0] + g * 512);
      gl2lds16(kl_p + (size_t)(kbase + r) * HD + cp8, &Kl[0][0] + g * 512);
      gl2lds16(vt_p + (size_t)r * SEQ + kbase + cp8, &Vt[0][0] + g * 512);
    }
    __syncthreads();

    // S^T = K·Q^T (3-term split fp16), both q-groups share K fragments
    floatx4 sacc[2][4];
    #pragma unroll
    for (int nt = 0; nt < 4; nt++) {
      const int r7 = l15 & 7;
      half8 akh0 = *(const half8*)&Kh[nt * 16 + l15][((0 * 4 + quad) ^ r7) * 8];
      half8 akh1 = *(const half8*)&Kh[nt * 16 + l15][((1 * 4 + quad) ^ r7) * 8];
      half8 akl0 = *(const half8*)&Kl[nt * 16 + l15][((0 * 4 + quad) ^ r7) * 8];
      half8 akl1 = *(const half8*)&Kl[nt * 16 + l15][((1 * 4 + quad) ^ r7) * 8];
      #pragma unroll
      for (int g = 0; g < 2; g++) {
        floatx4 s4 = (floatx4){0.f, 0.f, 0.f, 0.f};
        s4 = MFMA_F16(akh0, bqh[g][0], s4);
        s4 = MFMA_F16(akh1, bqh[g][1], s4);
        s4 = MFMA_F16(akh0, bql[g][0], s4);
        s4 = MFMA_F16(akh1, bql[g][1], s4);
        s4 = MFMA_F16(akl0, bqh[g][0], s4);
        s4 = MFMA_F16(akl1, bqh[g][1], s4);
        sacc[g][nt] = s4;
      }
    }

    // V A-fragments (permuted image), shared by both q-groups
    half8 av[4][2];
    {
      const int r7 = l15 & 7;
      #pragma unroll
      for (int nd = 0; nd < 4; nd++) {
        av[nd][0] = *(const half8*)&Vt[nd * 16 + l15][((0 * 4 + quad) ^ r7) * 8];
        av[nd][1] = *(const half8*)&Vt[nd * 16 + l15][((1 * 4 + quad) ^ r7) * 8];
      }
    }

    #pragma unroll
    for (int g = 0; g < 2; g++) {
      // online softmax over 64 keys: in-lane + 2 cross-quad shuffles
      float rmax = sacc[g][0][0];
      #pragma unroll
      for (int nt = 0; nt < 4; nt++)
        #pragma unroll
        for (int r = 0; r < 4; r++) rmax = fmaxf(rmax, sacc[g][nt][r]);
      rmax = fmaxf(rmax, __shfl_xor(rmax, 16, 64));
      rmax = fmaxf(rmax, __shfl_xor(rmax, 32, 64));
      const float mnew = fmaxf(m_[g], rmax);
      const float alpha = exp2f(m_[g] - mnew);
      m_[g] = mnew;

      float rsum = 0.f;
      #pragma unroll
      for (int nt = 0; nt < 4; nt++)
        #pragma unroll
        for (int r = 0; r < 4; r++) {
          float p = exp2f(sacc[g][nt][r] - mnew);
          sacc[g][nt][r] = p;
          rsum += p;
        }
      rsum += __shfl_xor(rsum, 16, 64);
      rsum += __shfl_xor(rsum, 32, 64);
      l_[g] = l_[g] * alpha + rsum;

      // P pack for PV B-operand: bp8[kc][j] = p[2kc + (j>>2)][j&3] (in-lane)
      half8 bp8[2];
      #pragma unroll
      for (int kc = 0; kc < 2; kc++)
        #pragma unroll
        for (int j = 0; j < 8; j++)
          bp8[kc][j] = (_Float16)sacc[g][2 * kc + (j >> 2)][j & 3];

      #pragma unroll
      for (int nd = 0; nd < 4; nd++) {
        Oacc[g][nd][0] *= alpha; Oacc[g][nd][1] *= alpha;
        Oacc[g][nd][2] *= alpha; Oacc[g][nd][3] *= alpha;
        Oacc[g][nd] = MFMA_F16(av[nd][0], bp8[0], Oacc[g][nd]);
        Oacc[g][nd] = MFMA_F16(av[nd][1], bp8[1], Oacc[g][nd]);
      }
    }
  }

  // epilogue: unnormalized O^T partial + (m,l)
  const size_t fqbase = (size_t)bh * SEQ + qrow0;
  #pragma unroll
  for (int g = 0; g < 2; g++) {
    const size_t fq = fqbase + g * 16 + l15;
    float* ob = Op + ((size_t)kh * 65536 + fq) * HD;
    #pragma unroll
    for (int nd = 0; nd < 4; nd++) {
      float4 vv;
      vv.x = Oacc[g][nd][0]; vv.y = Oacc[g][nd][1];
      vv.z = Oacc[g][nd][2]; vv.w = Oacc[g][nd][3];
      *(float4*)(ob + nd * 16 + quad * 4) = vv;
    }
    if (quad == 0) ml[kh * 65536 + fq] = make_float2(m_[g], l_[g]);
  }
}

// ---------------- merge the two split-K partials ----------------
__global__ __launch_bounds__(256) void merge_kernel(const float* __restrict__ Op,
                                                    const float2* __restrict__ ml,
                                                    float* __restrict__ out)
{
  const int tid = threadIdx.x;
  const int fq = blockIdx.x * 64 + (tid >> 2);
  const int dp = (tid & 3) * 16;
  float2 m0 = ml[fq], m1 = ml[65536 + fq];
  float M = fmaxf(m0.x, m1.x);
  float w0 = exp2f(m0.x - M), w1 = exp2f(m1.x - M);
  float rinv = 1.0f / (m0.y * w0 + m1.y * w1);
  int bh = fq >> 11, s = fq & 2047, b = bh >> 4, h = bh & 15;
  float* ob = out + ((size_t)(b * SEQ + s)) * DM + h * HD + dp;
  const float* p0 = Op + (size_t)fq * HD + dp;
  const float* p1 = p0 + (size_t)65536 * HD;
  #pragma unroll
  for (int j = 0; j < 4; j++) {
    float4 a = *(const float4*)(p0 + 4 * j);
    float4 c = *(const float4*)(p1 + 4 * j);
    float4 r;
    r.x = (a.x * w0 + c.x * w1) * rinv;
    r.y = (a.y * w0 + c.y * w1) * rinv;
    r.z = (a.z * w0 + c.z * w1) * rinv;
    r.w = (a.w * w0 + c.w * w1) * rinv;
    *(float4*)(ob + 4 * j) = r;
  }
}

extern "C" void kernel_launch(void* const* d_in, const int* in_sizes, int n_in,
                              void* d_out, int out_size, void* d_ws, size_t ws_size,
                              hipStream_t stream) {
  const float* q  = (const float*)d_in[0];
  const float* k  = (const float*)d_in[1];
  const float* v  = (const float*)d_in[2];
  const float* Wq = (const float*)d_in[3];
  const float* Wk = (const float*)d_in[4];
  const float* Wv = (const float*)d_in[5];
  float* out = (float*)d_out;

  char* W = (char*)d_ws;
  const size_t MiB = 1ull << 20;
  _Float16* qh_hi = (_Float16*)(W + 0 * MiB);
  _Float16* qh_lo = (_Float16*)(W + 8 * MiB);
  _Float16* kh_hi = (_Float16*)(W + 16 * MiB);
  _Float16* kh_lo = (_Float16*)(W + 24 * MiB);
  _Float16* vhT   = (_Float16*)(W + 32 * MiB);
  _Float16* vh    = (_Float16*)(W + 40 * MiB);  // dead after transpose_v
  _Float16* xh    = (_Float16*)(W + 48 * MiB);  // dead after last proj
  _Float16* xl    = (_Float16*)(W + 56 * MiB);
  _Float16* Wh    = (_Float16*)(W + 64 * MiB);
  _Float16* Wl    = (_Float16*)(W + 66 * MiB);
  float*    Op    = (float*)  (W + 40 * MiB);   // 2 x 16 MiB, aliases vh/xh/xl/Wh/Wl
  float2*   mlp   = (float2*) (W + 72 * MiB);   // 1 MiB; total 73 MiB

  // Q
  convert_kernel<<<5120, 256, 0, stream>>>(q, Wq, xh, xl, Wh, Wl, 1);
  proj_kernel<<<dim3(32, 8), 256, 0, stream>>>(xh, xl, Wh, Wl, qh_hi, qh_lo, QSCALE, 1);
  // K
  convert_kernel<<<5120, 256, 0, stream>>>(k, Wk, xh, xl, Wh, Wl, 1);
  proj_kernel<<<dim3(32, 8), 256, 0, stream>>>(xh, xl, Wh, Wl, kh_hi, kh_lo, 1.0f, 1);
  // V (single-term)
  convert_kernel<<<5120, 256, 0, stream>>>(v, Wv, xh, xl, Wh, Wl, 0);
  proj_kernel<<<dim3(32, 8), 256, 0, stream>>>(xh, xl, Wh, Wl, vh, vh, 1.0f, 0);

  transpose_v<<<dim3(32, 16), 256, 0, stream>>>(vh, vhT);
  flash_kernel<<<1024, 256, 0, stream>>>(qh_hi, qh_lo, kh_hi, kh_lo, vhT, Op, mlp);
  merge_kernel<<<1024, 256, 0, stream>>>(Op, mlp, out);
}